// Round 10
// baseline (1917.188 us; speedup 1.0000x reference)
//
#include <hip/hip_runtime.h>
#include <hip/hip_bf16.h>
#include <cstddef>
#include <cstdint>

#define N_NODES   100000
#define M_PAD     100096   /* 32 * 3128 */
#define N_EDGES   1600000
#define N_GRAPHS  4096
#define HID       512
#define OUT_DIM   12

typedef unsigned short u16;
typedef __attribute__((ext_vector_type(8))) short bf16x8;
typedef __attribute__((ext_vector_type(4))) float f32x4;

// ---------------------------------------------------------------------------
// bf16 <-> f32 helpers (storage is u16 bits, math fp32)
// ---------------------------------------------------------------------------
__device__ inline float bf2f(u16 u) {
    union { uint32_t i; float f; } v; v.i = (uint32_t)u << 16; return v.f;
}
__device__ inline u16 f2bf(float f) {  // round-to-nearest-even, finite inputs
    union { float f; uint32_t i; } v; v.f = f;
    uint32_t r = v.i + 0x7FFFu + ((v.i >> 16) & 1u);
    return (u16)(r >> 16);
}

__device__ inline void load8_bf(const u16* p, float o[8]) {
    uint4 u = *(const uint4*)p;
    uint32_t w[4] = {u.x, u.y, u.z, u.w};
    #pragma unroll
    for (int i = 0; i < 4; ++i) {
        o[2*i]   = bf2f((u16)(w[i] & 0xFFFFu));
        o[2*i+1] = bf2f((u16)(w[i] >> 16));
    }
}
__device__ inline void store8_bf(u16* p, const float o[8]) {
    uint4 u;
    u.x = (uint32_t)f2bf(o[0]) | ((uint32_t)f2bf(o[1]) << 16);
    u.y = (uint32_t)f2bf(o[2]) | ((uint32_t)f2bf(o[3]) << 16);
    u.z = (uint32_t)f2bf(o[4]) | ((uint32_t)f2bf(o[5]) << 16);
    u.w = (uint32_t)f2bf(o[6]) | ((uint32_t)f2bf(o[7]) << 16);
    *(uint4*)p = u;
}
// nontemporal 16B store of 8 packed bf16
__device__ inline void store8_bf_nt(u16* p, const float o[8]) {
    unsigned long long lo =
        (unsigned long long)((uint32_t)f2bf(o[0]) | ((uint32_t)f2bf(o[1]) << 16)) |
        ((unsigned long long)((uint32_t)f2bf(o[2]) | ((uint32_t)f2bf(o[3]) << 16)) << 32);
    unsigned long long hi =
        (unsigned long long)((uint32_t)f2bf(o[4]) | ((uint32_t)f2bf(o[5]) << 16)) |
        ((unsigned long long)((uint32_t)f2bf(o[6]) | ((uint32_t)f2bf(o[7]) << 16)) << 32);
    __builtin_nontemporal_store(lo, (unsigned long long*)p);
    __builtin_nontemporal_store(hi, (unsigned long long*)(p + 4));
}

// global -> LDS direct copy, 16 B per lane (per-lane global src, uniform LDS base)
__device__ inline void gld16(const void* g, void* l) {
    __builtin_amdgcn_global_load_lds(
        (const __attribute__((address_space(1))) void*)g,
        (__attribute__((address_space(3))) void*)(uint32_t)(uintptr_t)l,
        16, 0, 0);
}

// ---------------------------------------------------------------------------
// CSR build
// ---------------------------------------------------------------------------
__global__ void zero_ints(int* __restrict__ p, int n) {
    int i = blockIdx.x * blockDim.x + threadIdx.x;
    if (i < n) p[i] = 0;
}

__global__ void hist_kernel(const int* __restrict__ dst, int* __restrict__ counts) {
    int e = blockIdx.x * blockDim.x + threadIdx.x;
    if (e < N_EDGES) atomicAdd(&counts[dst[e]], 1);
}

#define SCAN_NB 98   /* ceil(100000/1024) */

__global__ __launch_bounds__(1024) void scan_chunks(const int* __restrict__ counts,
                                                    int* __restrict__ row_start,
                                                    int* __restrict__ partials) {
    __shared__ int smem[1024];
    int tid = threadIdx.x;
    int i = blockIdx.x * 1024 + tid;
    int v = (i < N_NODES) ? counts[i] : 0;
    smem[tid] = v;
    __syncthreads();
    for (int off = 1; off < 1024; off <<= 1) {
        int t = (tid >= off) ? smem[tid - off] : 0;
        __syncthreads();
        smem[tid] += t;
        __syncthreads();
    }
    if (i < N_NODES) row_start[i + 1] = smem[tid];
    if (tid == 1023) partials[blockIdx.x] = smem[1023];
}

__global__ void scan_partials(int* __restrict__ partials) {
    if (threadIdx.x == 0 && blockIdx.x == 0) {
        int run = 0;
        for (int b = 0; b < SCAN_NB; ++b) {
            int t = partials[b];
            partials[b] = run;
            run += t;
        }
    }
}

__global__ __launch_bounds__(1024) void scan_add_offsets(int* __restrict__ row_start,
                                                         const int* __restrict__ partials) {
    int i = blockIdx.x * 1024 + threadIdx.x;
    if (i == 0) row_start[0] = 0;
    if (i < N_NODES) row_start[i + 1] += partials[blockIdx.x];
}

__global__ void cursor_init(const int* __restrict__ row_start, int* __restrict__ cursor) {
    int i = blockIdx.x * blockDim.x + threadIdx.x;
    if (i < N_NODES) cursor[i] = row_start[i];
}

__global__ void scatter_edges(const int* __restrict__ src, const int* __restrict__ dst,
                              int* __restrict__ cursor, int* __restrict__ sorted_src) {
    int e = blockIdx.x * blockDim.x + threadIdx.x;
    if (e < N_EDGES) {
        int p = atomicAdd(&cursor[dst[e]], 1);
        p = min(max(p, 0), N_EDGES - 1);
        sorted_src[p] = src[e];
    }
}

// ---------------------------------------------------------------------------
// Weight prep: Wt[n][k] = bf16(W[k][n]), all 5 layer weights in one launch
// ---------------------------------------------------------------------------
__global__ __launch_bounds__(256) void transpose5_to_bf16(const float* __restrict__ W0,
                                                          const float* __restrict__ W1,
                                                          const float* __restrict__ W2,
                                                          const float* __restrict__ W3,
                                                          const float* __restrict__ W4,
                                                          u16* __restrict__ Wt) {
    __shared__ float t[32][33];
    const float* Ws[5] = {W0, W1, W2, W3, W4};
    const float* W = Ws[blockIdx.z];
    u16* dst = Wt + (size_t)blockIdx.z * HID * HID;
    int bx = blockIdx.x * 32, by = blockIdx.y * 32;
    int tx = threadIdx.x & 31, ty = threadIdx.x >> 5;
    #pragma unroll
    for (int i = 0; i < 32; i += 8)
        t[ty + i][tx] = W[(size_t)(by + ty + i) * HID + bx + tx];
    __syncthreads();
    #pragma unroll
    for (int i = 0; i < 32; i += 8)
        dst[(size_t)(bx + ty + i) * HID + by + tx] = f2bf(t[tx][ty + i]);
}

// ---------------------------------------------------------------------------
// Aggregation: out[n] = x[n] + sum_{in-edges} x[src]
// One wave per node (best measured variant), 16 B/lane, nt stores.
// ---------------------------------------------------------------------------
__global__ __launch_bounds__(256) void agg_full(const u16* __restrict__ X,
                                                const int* __restrict__ row_start,
                                                const int* __restrict__ sorted_src,
                                                u16* __restrict__ Out) {
    int node = blockIdx.x * 4 + (threadIdx.x >> 6);
    if (node >= N_NODES) return;
    int lane = threadIdx.x & 63;
    float acc[8];
    load8_bf(X + (size_t)node * HID + lane * 8, acc);
    int e0 = min(row_start[node], N_EDGES);
    int e1 = min(row_start[node + 1], N_EDGES);
    for (int e = e0; e < e1; ++e) {
        unsigned si = min((unsigned)sorted_src[e], (unsigned)(N_NODES - 1));
        float v[8];
        load8_bf(X + (size_t)si * HID + lane * 8, v);
        #pragma unroll
        for (int k = 0; k < 8; ++k) acc[k] += v[k];
    }
    store8_bf_nt(Out + (size_t)node * HID + lane * 8, acc);
}

// layer-1 7-dim aggregation
__global__ __launch_bounds__(64) void agg7_kernel(const float* __restrict__ x,
                                                  const int* __restrict__ row_start,
                                                  const int* __restrict__ sorted_src,
                                                  float* __restrict__ out) {
    int node = blockIdx.x * 8 + (threadIdx.x >> 3);
    int d = threadIdx.x & 7;
    if (node >= N_NODES || d >= 7) return;
    float acc = x[(size_t)node * 7 + d];
    int e0 = min(row_start[node], N_EDGES);
    int e1 = min(row_start[node + 1], N_EDGES);
    for (int e = e0; e < e1; ++e) {
        unsigned si = min((unsigned)sorted_src[e], (unsigned)(N_NODES - 1));
        acc += x[(size_t)si * 7 + d];
    }
    out[(size_t)node * 7 + d] = acc;
}

// ---------------------------------------------------------------------------
// Layer-1 K=7 GEMM: C = relu(A7 @ W + b). 128 nodes/block, W+bias in LDS.
// ---------------------------------------------------------------------------
__global__ __launch_bounds__(256) void gemm_k7_relu(const float* __restrict__ A7,
                                                    const float* __restrict__ W,
                                                    const float* __restrict__ bias,
                                                    u16* __restrict__ C) {
    __shared__ float Wl[7 * HID];
    __shared__ float Bi[HID];
    __shared__ float A7l[128 * 7];
    int tid = threadIdx.x;
    int node0 = blockIdx.x * 128;
    for (int t = tid; t < 7 * HID; t += 256) Wl[t] = W[t];
    for (int t = tid; t < HID; t += 256) Bi[t] = bias[t];
    for (int t = tid; t < 128 * 7; t += 256) {
        int gi = node0 * 7 + t;
        A7l[t] = (gi < N_NODES * 7) ? A7[gi] : 0.f;
    }
    __syncthreads();
    int wid = tid >> 6, lane = tid & 63;
    for (int it = 0; it < 32; ++it) {
        int nl = it * 4 + wid;
        int node = node0 + nl;
        if (node >= N_NODES) break;
        float a[7];
        #pragma unroll
        for (int k = 0; k < 7; ++k) a[k] = A7l[nl * 7 + k];
        float s[8];
        int c0 = lane * 8;
        #pragma unroll
        for (int c = 0; c < 8; ++c) {
            float v = Bi[c0 + c];
            #pragma unroll
            for (int k = 0; k < 7; ++k) v = fmaf(a[k], Wl[k * HID + c0 + c], v);
            s[c] = fmaxf(v, 0.f);
        }
        store8_bf(C + (size_t)node * HID + c0, s);
    }
}

// ---------------------------------------------------------------------------
// MFMA bf16 GEMM, BARRIER-FREE K-loop: C[M x 512] = relu(A @ W + bias).
// BM=32, BN=512 (full width): A tile (32x512, padded rows [32][520] -> 2-way
// max bank aliasing) staged ONCE via gld16 (one per row, per-lane global src);
// then 16 K-steps with NO barriers: a-frags from LDS, B-frags direct from L2
// (Wt = 512 KB, L2-resident) -- compiler pipelines B loads across K-steps.
// A read from HBM exactly once (no col-tile refetch). Epilogue via LDS repack.
// ---------------------------------------------------------------------------
#define LDW 520   /* u16 per LDS row: 1040 B stride = +4 banks/row */

template <bool RELU>
__global__ __launch_bounds__(256) void gemm_fullw(const u16* __restrict__ A,
                                                  const u16* __restrict__ Wt,
                                                  const float* __restrict__ bias,
                                                  u16* __restrict__ C) {
    __shared__ u16 As[32][LDW];                       // 33.3 KB
    const int tid  = threadIdx.x;
    const int wid  = tid >> 6;           // 0..3: col group of 128
    const int lane = tid & 63;
    const int l15 = lane & 15;
    const int l4  = lane >> 4;           // 0..3
    const int row0 = blockIdx.x * 32;

    // ---- stage A once: each wave loads rows wid*8 .. wid*8+7 ----
    #pragma unroll
    for (int r = 0; r < 8; ++r) {
        int row = wid * 8 + r;
        gld16(A + (size_t)(row0 + row) * HID + lane * 8, &As[row][0]);
    }
    __syncthreads();

    // ---- B fragment pointers (direct from L2) + bias ----
    const u16* Bp[8];
    float bcol[8];
    #pragma unroll
    for (int n = 0; n < 8; ++n) {
        int col = wid * 128 + n * 16 + l15;
        Bp[n]  = Wt + (size_t)col * HID + l4 * 8;
        bcol[n] = bias[col];
    }

    f32x4 acc[2][8] = {};

    // ---- barrier-free K loop ----
    #pragma unroll 4
    for (int kt = 0; kt < 16; ++kt) {
        bf16x8 bfr[8];
        #pragma unroll
        for (int n = 0; n < 8; ++n)
            bfr[n] = *(const bf16x8*)(Bp[n] + kt * 32);
        bf16x8 af[2];
        #pragma unroll
        for (int m = 0; m < 2; ++m)
            af[m] = *(const bf16x8*)&As[m * 16 + l15][kt * 32 + l4 * 8];
        #pragma unroll
        for (int m = 0; m < 2; ++m)
            #pragma unroll
            for (int n = 0; n < 8; ++n)
                acc[m][n] = __builtin_amdgcn_mfma_f32_16x16x32_bf16(af[m], bfr[n],
                                                                    acc[m][n], 0, 0, 0);
    }

    // ---- epilogue: repack through LDS -> coalesced uint4 stores ----
    __syncthreads();                      // all reads of As done
    #pragma unroll
    for (int m = 0; m < 2; ++m)
        #pragma unroll
        for (int n = 0; n < 8; ++n) {
            int c = wid * 128 + n * 16 + l15;
            #pragma unroll
            for (int i = 0; i < 4; ++i) {
                float v = acc[m][n][i] + bcol[n];
                if (RELU) v = fmaxf(v, 0.f);
                As[m * 16 + l4 * 4 + i][c] = f2bf(v);
            }
        }
    __syncthreads();
    #pragma unroll
    for (int j = 0; j < 8; ++j) {
        int c = tid + j * 256;            // 2048 chunks of 16 B
        int r = c >> 6, cc = (c & 63) * 8;
        uint4 v = *(const uint4*)&As[r][cc];
        *(uint4*)&C[(size_t)(row0 + r) * HID + cc] = v;
    }
}

// ---------------------------------------------------------------------------
// fp32 tiled GEMM (head only)
// ---------------------------------------------------------------------------
template <bool RELU>
__global__ __launch_bounds__(256) void gemm_tiled_f32(const float* __restrict__ A,
                                                      const float* __restrict__ W,
                                                      const float* __restrict__ bias,
                                                      float* __restrict__ C,
                                                      int M, int N, int K) {
    __shared__ float As[16][68];
    __shared__ float Bs[16][68];
    int tid = threadIdx.x;
    int tx = tid & 15, ty = tid >> 4;
    int col0 = blockIdx.x * 64;
    int row0 = blockIdx.y * 64;
    float acc[4][4] = {};

    for (int k0 = 0; k0 < K; k0 += 16) {
        {
            int r = tid >> 2, c = (tid & 3) * 4;
            float4 v = make_float4(0.f, 0.f, 0.f, 0.f);
            int gr = row0 + r;
            if (gr < M) v = *reinterpret_cast<const float4*>(A + (size_t)gr * K + k0 + c);
            As[c + 0][r] = v.x; As[c + 1][r] = v.y; As[c + 2][r] = v.z; As[c + 3][r] = v.w;
        }
        {
            int r = tid >> 4, c = (tid & 15) * 4;
            int gc = col0 + c;
            float4 v = make_float4(0.f, 0.f, 0.f, 0.f);
            const float* wp = W + (size_t)(k0 + r) * N + gc;
            if (gc + 3 < N) {
                v = *reinterpret_cast<const float4*>(wp);
            } else {
                float t0 = (gc + 0 < N) ? wp[0] : 0.f;
                float t1 = (gc + 1 < N) ? wp[1] : 0.f;
                float t2 = (gc + 2 < N) ? wp[2] : 0.f;
                v = make_float4(t0, t1, t2, 0.f);
            }
            *reinterpret_cast<float4*>(&Bs[r][c]) = v;
        }
        __syncthreads();
        #pragma unroll
        for (int k = 0; k < 16; ++k) {
            float a[4], b[4];
            *(float4*)a = *(const float4*)&As[k][ty * 4];
            *(float4*)b = *(const float4*)&Bs[k][tx * 4];
            #pragma unroll
            for (int i = 0; i < 4; ++i)
                #pragma unroll
                for (int j = 0; j < 4; ++j)
                    acc[i][j] = fmaf(a[i], b[j], acc[i][j]);
        }
        __syncthreads();
    }

    #pragma unroll
    for (int i = 0; i < 4; ++i) {
        int r = row0 + ty * 4 + i;
        if (r >= M) break;
        #pragma unroll
        for (int j = 0; j < 4; ++j) {
            int cidx = col0 + tx * 4 + j;
            if (cidx >= N) continue;
            float v = acc[i][j] + bias[cidx];
            if (RELU) v = fmaxf(v, 0.f);
            C[(size_t)r * N + cidx] = v;
        }
    }
}

// ---------------------------------------------------------------------------
// Pooling
// ---------------------------------------------------------------------------
__global__ void graph_bounds(const int* __restrict__ batch, int* __restrict__ g_start) {
    int g = blockIdx.x * blockDim.x + threadIdx.x;
    if (g > N_GRAPHS) return;
    int lo = 0, hi = N_NODES;
    while (lo < hi) {
        int mid = (lo + hi) >> 1;
        if (batch[mid] < g) lo = mid + 1; else hi = mid;
    }
    g_start[g] = lo;
}

__global__ __launch_bounds__(256) void pool_kernel(const u16* __restrict__ H,
                                                   const int* __restrict__ g_start,
                                                   float* __restrict__ pooled) {
    int g = blockIdx.x * 4 + (threadIdx.x >> 6);
    if (g >= N_GRAPHS) return;
    int lane = threadIdx.x & 63;
    int s = g_start[g], e = g_start[g + 1];
    float acc[8] = {};
    for (int n = s; n < e; ++n) {
        float v[8];
        load8_bf(H + (size_t)n * HID + lane * 8, v);
        #pragma unroll
        for (int k = 0; k < 8; ++k) acc[k] += v[k];
    }
    float inv = 1.f / fmaxf((float)(e - s), 1.f);
    float* o = pooled + (size_t)g * HID + lane * 8;
    #pragma unroll
    for (int k = 0; k < 8; ++k) o[k] = acc[k] * inv;
}

// ---------------------------------------------------------------------------
// Diagnostic fallback
// ---------------------------------------------------------------------------
__global__ void diag_kernel(float* __restrict__ out, int n, float v) {
    int i = blockIdx.x * blockDim.x + threadIdx.x;
    if (i < n) out[i] = v;
}

// ---------------------------------------------------------------------------
// Launch
// ---------------------------------------------------------------------------
static inline size_t rnd256(size_t b) { return (b + 255) & ~(size_t)255; }

extern "C" void kernel_launch(void* const* d_in, const int* in_sizes, int n_in,
                              void* d_out, int out_size, void* d_ws, size_t ws_size,
                              hipStream_t stream) {
    (void)in_sizes; (void)n_in;
    const float* x     = (const float*)d_in[0];
    const int*   ei    = (const int*)d_in[1];
    const int*   batch = (const int*)d_in[2];
    const int* src = ei;
    const int* dst = ei + N_EDGES;

    const float* c1_w1 = (const float*)d_in[3];
    const float* c1_b1 = (const float*)d_in[4];
    const float* c1_w2 = (const float*)d_in[5];
    const float* c1_b2 = (const float*)d_in[6];
    const float* c2_w1 = (const float*)d_in[7];
    const float* c2_b1 = (const float*)d_in[8];
    const float* c2_w2 = (const float*)d_in[9];
    const float* c2_b2 = (const float*)d_in[10];
    const float* c3_w1 = (const float*)d_in[11];
    const float* c3_b1 = (const float*)d_in[12];
    const float* c3_w2 = (const float*)d_in[13];
    const float* c3_b2 = (const float*)d_in[14];
    const float* lin_w1 = (const float*)d_in[15];
    const float* lin_b1 = (const float*)d_in[16];
    const float* lin_w2 = (const float*)d_in[17];
    const float* lin_b2 = (const float*)d_in[18];
    float* out = (float*)d_out;

    size_t off = 0;
    auto alloc = [&](size_t bytes) -> void* {
        void* p = (char*)d_ws + off;
        off += rnd256(bytes);
        return p;
    };
    u16*   b0        = (u16*)alloc((size_t)M_PAD * HID * 2);
    u16*   b1        = (u16*)alloc((size_t)M_PAD * HID * 2);
    float* agg7buf   = (float*)alloc((size_t)N_NODES * 7 * 4);
    int*   counts    = (int*)alloc((size_t)N_NODES * 4);
    int*   cursor    = (int*)alloc((size_t)N_NODES * 4);
    int*   row_start = (int*)alloc((size_t)(N_NODES + 1) * 4);
    int*   sorted_src= (int*)alloc((size_t)N_EDGES * 4);
    int*   g_start   = (int*)alloc((size_t)(N_GRAPHS + 1) * 4);
    int*   partials  = (int*)alloc((size_t)SCAN_NB * 4);
    float* pooled    = (float*)alloc((size_t)N_GRAPHS * HID * 4);
    char*  hh_slot   = (char*)alloc((size_t)N_GRAPHS * 256 * 4);
    float* hh        = (float*)hh_slot;
    u16*   wt        = (u16*)hh_slot;
    u16* c1w2T = wt + 0 * HID * HID;
    u16* c2w1T = wt + 1 * HID * HID;
    u16* c2w2T = wt + 2 * HID * HID;
    u16* c3w1T = wt + 3 * HID * HID;
    u16* c3w2T = wt + 4 * HID * HID;

    if (off > ws_size) {
        diag_kernel<<<(out_size + 255) / 256, 256, 0, stream>>>(
            out, out_size, (float)(ws_size >> 20));
        return;
    }

    // --- CSR build + weight prep ---
    zero_ints<<<(N_NODES + 255) / 256, 256, 0, stream>>>(counts, N_NODES);
    hist_kernel<<<(N_EDGES + 255) / 256, 256, 0, stream>>>(dst, counts);
    scan_chunks<<<SCAN_NB, 1024, 0, stream>>>(counts, row_start, partials);
    scan_partials<<<1, 64, 0, stream>>>(partials);
    scan_add_offsets<<<SCAN_NB, 1024, 0, stream>>>(row_start, partials);
    cursor_init<<<(N_NODES + 255) / 256, 256, 0, stream>>>(row_start, cursor);
    scatter_edges<<<(N_EDGES + 255) / 256, 256, 0, stream>>>(src, dst, cursor, sorted_src);
    graph_bounds<<<(N_GRAPHS + 256) / 256, 256, 0, stream>>>(batch, g_start);
    transpose5_to_bf16<<<dim3(HID / 32, HID / 32, 5), 256, 0, stream>>>(
        c1_w2, c2_w1, c2_w2, c3_w1, c3_w2, wt);

    const int mgrid = M_PAD / 32;         // 3128 blocks
    const int aggGrid = N_NODES / 4;      // 25000

    // --- Layer 1 ---
    agg7_kernel<<<(N_NODES + 7) / 8, 64, 0, stream>>>(x, row_start, sorted_src, agg7buf);
    gemm_k7_relu<<<(N_NODES + 127) / 128, 256, 0, stream>>>(agg7buf, c1_w1, c1_b1, b0);
    gemm_fullw<true><<<mgrid, 256, 0, stream>>>(b0, c1w2T, c1_b2, b1);
    // --- Layer 2 ---
    agg_full<<<aggGrid, 256, 0, stream>>>(b1, row_start, sorted_src, b0);
    gemm_fullw<true><<<mgrid, 256, 0, stream>>>(b0, c2w1T, c2_b1, b1);
    gemm_fullw<true><<<mgrid, 256, 0, stream>>>(b1, c2w2T, c2_b2, b0);
    // --- Layer 3 ---
    agg_full<<<aggGrid, 256, 0, stream>>>(b0, row_start, sorted_src, b1);
    gemm_fullw<true><<<mgrid, 256, 0, stream>>>(b1, c3w1T, c3_b1, b0);
    gemm_fullw<true><<<mgrid, 256, 0, stream>>>(b0, c3w2T, c3_b2, b1);
    // --- Pool + head (fp32) ---
    pool_kernel<<<N_GRAPHS / 4, 256, 0, stream>>>(b1, g_start, pooled);
    gemm_tiled_f32<true><<<dim3(256 / 64, N_GRAPHS / 64), 256, 0, stream>>>(
        pooled, lin_w1, lin_b1, hh, N_GRAPHS, 256, HID);
    gemm_tiled_f32<false><<<dim3(1, N_GRAPHS / 64), 256, 0, stream>>>(
        hh, lin_w2, lin_b2, out, N_GRAPHS, OUT_DIM, 256);
}

// Round 12
// 1372.428 us; speedup vs baseline: 1.3969x; 1.3969x over previous
//
#include <hip/hip_runtime.h>
#include <hip/hip_bf16.h>
#include <cstddef>
#include <cstdint>

#define N_NODES   100000
#define M_PAD     100096   /* 128 * 782 */
#define N_EDGES   1600000
#define N_GRAPHS  4096
#define HID       512
#define OUT_DIM   12

typedef unsigned short u16;
typedef __attribute__((ext_vector_type(8))) short bf16x8;
typedef __attribute__((ext_vector_type(4))) float f32x4;

// ---------------------------------------------------------------------------
// bf16 <-> f32 helpers (storage is u16 bits, math fp32)
// ---------------------------------------------------------------------------
__device__ inline float bf2f(u16 u) {
    union { uint32_t i; float f; } v; v.i = (uint32_t)u << 16; return v.f;
}
__device__ inline u16 f2bf(float f) {  // round-to-nearest-even, finite inputs
    union { float f; uint32_t i; } v; v.f = f;
    uint32_t r = v.i + 0x7FFFu + ((v.i >> 16) & 1u);
    return (u16)(r >> 16);
}

__device__ inline void load8_bf(const u16* p, float o[8]) {
    uint4 u = *(const uint4*)p;
    uint32_t w[4] = {u.x, u.y, u.z, u.w};
    #pragma unroll
    for (int i = 0; i < 4; ++i) {
        o[2*i]   = bf2f((u16)(w[i] & 0xFFFFu));
        o[2*i+1] = bf2f((u16)(w[i] >> 16));
    }
}
__device__ inline void store8_bf(u16* p, const float o[8]) {
    uint4 u;
    u.x = (uint32_t)f2bf(o[0]) | ((uint32_t)f2bf(o[1]) << 16);
    u.y = (uint32_t)f2bf(o[2]) | ((uint32_t)f2bf(o[3]) << 16);
    u.z = (uint32_t)f2bf(o[4]) | ((uint32_t)f2bf(o[5]) << 16);
    u.w = (uint32_t)f2bf(o[6]) | ((uint32_t)f2bf(o[7]) << 16);
    *(uint4*)p = u;
}
// nontemporal 16B store of 8 packed bf16
__device__ inline void store8_bf_nt(u16* p, const float o[8]) {
    unsigned long long lo =
        (unsigned long long)((uint32_t)f2bf(o[0]) | ((uint32_t)f2bf(o[1]) << 16)) |
        ((unsigned long long)((uint32_t)f2bf(o[2]) | ((uint32_t)f2bf(o[3]) << 16)) << 32);
    unsigned long long hi =
        (unsigned long long)((uint32_t)f2bf(o[4]) | ((uint32_t)f2bf(o[5]) << 16)) |
        ((unsigned long long)((uint32_t)f2bf(o[6]) | ((uint32_t)f2bf(o[7]) << 16)) << 32);
    __builtin_nontemporal_store(lo, (unsigned long long*)p);
    __builtin_nontemporal_store(hi, (unsigned long long*)(p + 4));
}

// global -> LDS direct copy, 16 B per lane (per-lane global src, uniform LDS base)
__device__ inline void gld16(const void* g, void* l) {
    __builtin_amdgcn_global_load_lds(
        (const __attribute__((address_space(1))) void*)g,
        (__attribute__((address_space(3))) void*)(uint32_t)(uintptr_t)l,
        16, 0, 0);
}

// ---------------------------------------------------------------------------
// CSR build
// ---------------------------------------------------------------------------
__global__ void zero_ints(int* __restrict__ p, int n) {
    int i = blockIdx.x * blockDim.x + threadIdx.x;
    if (i < n) p[i] = 0;
}

__global__ void hist_kernel(const int* __restrict__ dst, int* __restrict__ counts) {
    int e = blockIdx.x * blockDim.x + threadIdx.x;
    if (e < N_EDGES) atomicAdd(&counts[dst[e]], 1);
}

#define SCAN_NB 98   /* ceil(100000/1024) */

__global__ __launch_bounds__(1024) void scan_chunks(const int* __restrict__ counts,
                                                    int* __restrict__ row_start,
                                                    int* __restrict__ partials) {
    __shared__ int smem[1024];
    int tid = threadIdx.x;
    int i = blockIdx.x * 1024 + tid;
    int v = (i < N_NODES) ? counts[i] : 0;
    smem[tid] = v;
    __syncthreads();
    for (int off = 1; off < 1024; off <<= 1) {
        int t = (tid >= off) ? smem[tid - off] : 0;
        __syncthreads();
        smem[tid] += t;
        __syncthreads();
    }
    if (i < N_NODES) row_start[i + 1] = smem[tid];
    if (tid == 1023) partials[blockIdx.x] = smem[1023];
}

__global__ void scan_partials(int* __restrict__ partials) {
    if (threadIdx.x == 0 && blockIdx.x == 0) {
        int run = 0;
        for (int b = 0; b < SCAN_NB; ++b) {
            int t = partials[b];
            partials[b] = run;
            run += t;
        }
    }
}

__global__ __launch_bounds__(1024) void scan_add_offsets(int* __restrict__ row_start,
                                                         const int* __restrict__ partials) {
    int i = blockIdx.x * 1024 + threadIdx.x;
    if (i == 0) row_start[0] = 0;
    if (i < N_NODES) row_start[i + 1] += partials[blockIdx.x];
}

__global__ void cursor_init(const int* __restrict__ row_start, int* __restrict__ cursor) {
    int i = blockIdx.x * blockDim.x + threadIdx.x;
    if (i < N_NODES) cursor[i] = row_start[i];
}

__global__ void scatter_edges(const int* __restrict__ src, const int* __restrict__ dst,
                              int* __restrict__ cursor, int* __restrict__ sorted_src) {
    int e = blockIdx.x * blockDim.x + threadIdx.x;
    if (e < N_EDGES) {
        int p = atomicAdd(&cursor[dst[e]], 1);
        p = min(max(p, 0), N_EDGES - 1);
        sorted_src[p] = src[e];
    }
}

// ---------------------------------------------------------------------------
// Weight prep: Wt[n][k] = bf16(W[k][n]), all 5 layer weights in one launch
// ---------------------------------------------------------------------------
__global__ __launch_bounds__(256) void transpose5_to_bf16(const float* __restrict__ W0,
                                                          const float* __restrict__ W1,
                                                          const float* __restrict__ W2,
                                                          const float* __restrict__ W3,
                                                          const float* __restrict__ W4,
                                                          u16* __restrict__ Wt) {
    __shared__ float t[32][33];
    const float* Ws[5] = {W0, W1, W2, W3, W4};
    const float* W = Ws[blockIdx.z];
    u16* dst = Wt + (size_t)blockIdx.z * HID * HID;
    int bx = blockIdx.x * 32, by = blockIdx.y * 32;
    int tx = threadIdx.x & 31, ty = threadIdx.x >> 5;
    #pragma unroll
    for (int i = 0; i < 32; i += 8)
        t[ty + i][tx] = W[(size_t)(by + ty + i) * HID + bx + tx];
    __syncthreads();
    #pragma unroll
    for (int i = 0; i < 32; i += 8)
        dst[(size_t)(bx + ty + i) * HID + by + tx] = f2bf(t[tx][ty + i]);
}

// ---------------------------------------------------------------------------
// Aggregation: out[n] = x[n] + sum_{in-edges} x[src]
// One wave per node; edge loop unrolled x4 (4 independent row-gathers in
// flight per lane). nt stores.
// ---------------------------------------------------------------------------
__global__ __launch_bounds__(256) void agg_full(const u16* __restrict__ X,
                                                const int* __restrict__ row_start,
                                                const int* __restrict__ sorted_src,
                                                u16* __restrict__ Out) {
    int node = blockIdx.x * 4 + (threadIdx.x >> 6);
    if (node >= N_NODES) return;
    int lane = threadIdx.x & 63;
    const size_t coff = (size_t)lane * 8;
    float acc[8];
    load8_bf(X + (size_t)node * HID + coff, acc);
    int e0 = min(row_start[node], N_EDGES);
    int e1 = min(row_start[node + 1], N_EDGES);
    int e  = e0;
    int e4 = e0 + ((e1 - e0) & ~3);
    for (; e < e4; e += 4) {
        unsigned s0 = min((unsigned)sorted_src[e + 0], (unsigned)(N_NODES - 1));
        unsigned s1 = min((unsigned)sorted_src[e + 1], (unsigned)(N_NODES - 1));
        unsigned s2 = min((unsigned)sorted_src[e + 2], (unsigned)(N_NODES - 1));
        unsigned s3 = min((unsigned)sorted_src[e + 3], (unsigned)(N_NODES - 1));
        float v0[8], v1[8], v2[8], v3[8];
        load8_bf(X + (size_t)s0 * HID + coff, v0);
        load8_bf(X + (size_t)s1 * HID + coff, v1);
        load8_bf(X + (size_t)s2 * HID + coff, v2);
        load8_bf(X + (size_t)s3 * HID + coff, v3);
        #pragma unroll
        for (int k = 0; k < 8; ++k)
            acc[k] += (v0[k] + v1[k]) + (v2[k] + v3[k]);
    }
    for (; e < e1; ++e) {
        unsigned si = min((unsigned)sorted_src[e], (unsigned)(N_NODES - 1));
        float v[8];
        load8_bf(X + (size_t)si * HID + coff, v);
        #pragma unroll
        for (int k = 0; k < 8; ++k) acc[k] += v[k];
    }
    store8_bf_nt(Out + (size_t)node * HID + coff, acc);
}

// layer-1 7-dim aggregation
__global__ __launch_bounds__(64) void agg7_kernel(const float* __restrict__ x,
                                                  const int* __restrict__ row_start,
                                                  const int* __restrict__ sorted_src,
                                                  float* __restrict__ out) {
    int node = blockIdx.x * 8 + (threadIdx.x >> 3);
    int d = threadIdx.x & 7;
    if (node >= N_NODES || d >= 7) return;
    float acc = x[(size_t)node * 7 + d];
    int e0 = min(row_start[node], N_EDGES);
    int e1 = min(row_start[node + 1], N_EDGES);
    for (int e = e0; e < e1; ++e) {
        unsigned si = min((unsigned)sorted_src[e], (unsigned)(N_NODES - 1));
        acc += x[(size_t)si * 7 + d];
    }
    out[(size_t)node * 7 + d] = acc;
}

// ---------------------------------------------------------------------------
// Layer-1 K=7 GEMM: C = relu(A7 @ W + b). 128 nodes/block, W+bias in LDS.
// ---------------------------------------------------------------------------
__global__ __launch_bounds__(256) void gemm_k7_relu(const float* __restrict__ A7,
                                                    const float* __restrict__ W,
                                                    const float* __restrict__ bias,
                                                    u16* __restrict__ C) {
    __shared__ float Wl[7 * HID];
    __shared__ float Bi[HID];
    __shared__ float A7l[128 * 7];
    int tid = threadIdx.x;
    int node0 = blockIdx.x * 128;
    for (int t = tid; t < 7 * HID; t += 256) Wl[t] = W[t];
    for (int t = tid; t < HID; t += 256) Bi[t] = bias[t];
    for (int t = tid; t < 128 * 7; t += 256) {
        int gi = node0 * 7 + t;
        A7l[t] = (gi < N_NODES * 7) ? A7[gi] : 0.f;
    }
    __syncthreads();
    int wid = tid >> 6, lane = tid & 63;
    for (int it = 0; it < 32; ++it) {
        int nl = it * 4 + wid;
        int node = node0 + nl;
        if (node >= N_NODES) break;
        float a[7];
        #pragma unroll
        for (int k = 0; k < 7; ++k) a[k] = A7l[nl * 7 + k];
        float s[8];
        int c0 = lane * 8;
        #pragma unroll
        for (int c = 0; c < 8; ++c) {
            float v = Bi[c0 + c];
            #pragma unroll
            for (int k = 0; k < 7; ++k) v = fmaf(a[k], Wl[k * HID + c0 + c], v);
            s[c] = fmaxf(v, 0.f);
        }
        store8_bf(C + (size_t)node * HID + c0, s);
    }
}

// ---------------------------------------------------------------------------
// MFMA bf16 GEMM with COUNTED vmcnt (T4), race-fixed (r11 post-mortem):
// explicit s_waitcnt lgkmcnt(0) PINNED between the two raw barriers so
// every wave's ds_reads of buf[cur] are complete before any wave's next
// iteration overwrites it (volatile-asm program order + memory clobbers).
// vmcnt(4), not 0, in the main loop: next tile's 4 gld16 stay in flight
// across the barriers and the MFMAs.
// ---------------------------------------------------------------------------
template <bool RELU>
__global__ __launch_bounds__(256) void gemm_mfma_bf16(const u16* __restrict__ A,
                                                      const u16* __restrict__ Wt,
                                                      const float* __restrict__ bias,
                                                      u16* __restrict__ C) {
    __shared__ u16 smem[2 * 2 * 128 * 32];                   // 32 KB
    u16 (*As)[128][32] = (u16(*)[128][32])smem;              // As[0..1]
    u16 (*Bs)[128][32] = (u16(*)[128][32])(smem + 2 * 128 * 32);

    const int tid  = threadIdx.x;
    const int wid  = tid >> 6;
    const int lane = tid & 63;
    const int wr = wid >> 1, wc = wid & 1;
    const int row0 = blockIdx.y * 128;
    const int col0 = blockIdx.x * 128;
    const int l15 = lane & 15;
    const int l4  = lane >> 4;

    const int srow = lane >> 2;          // 0..15 within a 16-row stage group
    const int scol = (lane & 3) * 8;     // u16 offset within row (4 x 16 B)

    const u16* Ag0 = A  + (size_t)(row0 + wid * 32 + srow) * HID + scol;
    const u16* Bg0 = Wt + (size_t)(col0 + wid * 32 + srow) * HID + scol;

    auto stage = [&](int buf, int k0) {  // 4 gld16 per lane
        #pragma unroll
        for (int i = 0; i < 2; ++i) {
            gld16(Ag0 + (size_t)i * 16 * HID + k0, &As[buf][wid * 32 + i * 16][0]);
            gld16(Bg0 + (size_t)i * 16 * HID + k0, &Bs[buf][wid * 32 + i * 16][0]);
        }
    };

    f32x4 acc[4][4] = {};

    stage(0, 0);                          // 4 outstanding

    #pragma unroll
    for (int kt = 0; kt < 16; ++kt) {
        const int cur = kt & 1;
        if (kt < 15) {
            stage(cur ^ 1, (kt + 1) * 32);                    // 8 outstanding
            asm volatile("s_waitcnt vmcnt(4)" ::: "memory");  // cur's 4 landed
        } else {
            asm volatile("s_waitcnt vmcnt(0)" ::: "memory");  // last tile: drain
        }
        __builtin_amdgcn_s_barrier();         // A: buf[cur] visible to all waves
        __builtin_amdgcn_sched_barrier(0);    // no ds_read hoist above barrier

        bf16x8 af[4], bfr[4];
        #pragma unroll
        for (int m = 0; m < 4; ++m)
            af[m] = *(const bf16x8*)&As[cur][wr * 64 + m * 16 + l15][l4 * 8];
        #pragma unroll
        for (int n = 0; n < 4; ++n)
            bfr[n] = *(const bf16x8*)&Bs[cur][wc * 64 + n * 16 + l15][l4 * 8];
        asm volatile("s_waitcnt lgkmcnt(0)" ::: "memory");  // reads COMPLETE
        __builtin_amdgcn_sched_barrier(0);                  // pin before barrier B

        #pragma unroll
        for (int m = 0; m < 4; ++m)
            #pragma unroll
            for (int n = 0; n < 4; ++n)
                acc[m][n] = __builtin_amdgcn_mfma_f32_16x16x32_bf16(af[m], bfr[n],
                                                                    acc[m][n], 0, 0, 0);
        __builtin_amdgcn_s_barrier();         // B: safe to overwrite buf[cur]
    }

    // ---- epilogue: acc -> LDS (reuse the 32KB) -> coalesced uint4 stores ----
    u16* Ct = smem;                       // [128][128] u16 = 32 KB
    #pragma unroll
    for (int m = 0; m < 4; ++m) {
        #pragma unroll
        for (int n = 0; n < 4; ++n) {
            int col = wc * 64 + n * 16 + l15;
            float b = bias[col0 + col];
            #pragma unroll
            for (int i = 0; i < 4; ++i) {
                int r = wr * 64 + m * 16 + l4 * 4 + i;
                float v = acc[m][n][i] + b;
                if (RELU) v = fmaxf(v, 0.f);
                Ct[r * 128 + col] = f2bf(v);
            }
        }
    }
    __syncthreads();
    #pragma unroll
    for (int j = 0; j < 8; ++j) {
        int c = tid + j * 256;            // 2048 16B chunks
        int r = c >> 4, cc = (c & 15) * 8;
        uint4 v = *(const uint4*)&Ct[r * 128 + cc];
        *(uint4*)&C[(size_t)(row0 + r) * HID + col0 + cc] = v;
    }
}

// ---------------------------------------------------------------------------
// fp32 tiled GEMM (head only)
// ---------------------------------------------------------------------------
template <bool RELU>
__global__ __launch_bounds__(256) void gemm_tiled_f32(const float* __restrict__ A,
                                                      const float* __restrict__ W,
                                                      const float* __restrict__ bias,
                                                      float* __restrict__ C,
                                                      int M, int N, int K) {
    __shared__ float As[16][68];
    __shared__ float Bs[16][68];
    int tid = threadIdx.x;
    int tx = tid & 15, ty = tid >> 4;
    int col0 = blockIdx.x * 64;
    int row0 = blockIdx.y * 64;
    float acc[4][4] = {};

    for (int k0 = 0; k0 < K; k0 += 16) {
        {
            int r = tid >> 2, c = (tid & 3) * 4;
            float4 v = make_float4(0.f, 0.f, 0.f, 0.f);
            int gr = row0 + r;
            if (gr < M) v = *reinterpret_cast<const float4*>(A + (size_t)gr * K + k0 + c);
            As[c + 0][r] = v.x; As[c + 1][r] = v.y; As[c + 2][r] = v.z; As[c + 3][r] = v.w;
        }
        {
            int r = tid >> 4, c = (tid & 15) * 4;
            int gc = col0 + c;
            float4 v = make_float4(0.f, 0.f, 0.f, 0.f);
            const float* wp = W + (size_t)(k0 + r) * N + gc;
            if (gc + 3 < N) {
                v = *reinterpret_cast<const float4*>(wp);
            } else {
                float t0 = (gc + 0 < N) ? wp[0] : 0.f;
                float t1 = (gc + 1 < N) ? wp[1] : 0.f;
                float t2 = (gc + 2 < N) ? wp[2] : 0.f;
                v = make_float4(t0, t1, t2, 0.f);
            }
            *reinterpret_cast<float4*>(&Bs[r][c]) = v;
        }
        __syncthreads();
        #pragma unroll
        for (int k = 0; k < 16; ++k) {
            float a[4], b[4];
            *(float4*)a = *(const float4*)&As[k][ty * 4];
            *(float4*)b = *(const float4*)&Bs[k][tx * 4];
            #pragma unroll
            for (int i = 0; i < 4; ++i)
                #pragma unroll
                for (int j = 0; j < 4; ++j)
                    acc[i][j] = fmaf(a[i], b[j], acc[i][j]);
        }
        __syncthreads();
    }

    #pragma unroll
    for (int i = 0; i < 4; ++i) {
        int r = row0 + ty * 4 + i;
        if (r >= M) break;
        #pragma unroll
        for (int j = 0; j < 4; ++j) {
            int cidx = col0 + tx * 4 + j;
            if (cidx >= N) continue;
            float v = acc[i][j] + bias[cidx];
            if (RELU) v = fmaxf(v, 0.f);
            C[(size_t)r * N + cidx] = v;
        }
    }
}

// ---------------------------------------------------------------------------
// Pooling
// ---------------------------------------------------------------------------
__global__ void graph_bounds(const int* __restrict__ batch, int* __restrict__ g_start) {
    int g = blockIdx.x * blockDim.x + threadIdx.x;
    if (g > N_GRAPHS) return;
    int lo = 0, hi = N_NODES;
    while (lo < hi) {
        int mid = (lo + hi) >> 1;
        if (batch[mid] < g) lo = mid + 1; else hi = mid;
    }
    g_start[g] = lo;
}

__global__ __launch_bounds__(256) void pool_kernel(const u16* __restrict__ H,
                                                   const int* __restrict__ g_start,
                                                   float* __restrict__ pooled) {
    int g = blockIdx.x * 4 + (threadIdx.x >> 6);
    if (g >= N_GRAPHS) return;
    int lane = threadIdx.x & 63;
    int s = g_start[g], e = g_start[g + 1];
    float acc[8] = {};
    for (int n = s; n < e; ++n) {
        float v[8];
        load8_bf(H + (size_t)n * HID + lane * 8, v);
        #pragma unroll
        for (int k = 0; k < 8; ++k) acc[k] += v[k];
    }
    float inv = 1.f / fmaxf((float)(e - s), 1.f);
    float* o = pooled + (size_t)g * HID + lane * 8;
    #pragma unroll
    for (int k = 0; k < 8; ++k) o[k] = acc[k] * inv;
}

// ---------------------------------------------------------------------------
// Diagnostic fallback
// ---------------------------------------------------------------------------
__global__ void diag_kernel(float* __restrict__ out, int n, float v) {
    int i = blockIdx.x * blockDim.x + threadIdx.x;
    if (i < n) out[i] = v;
}

// ---------------------------------------------------------------------------
// Launch
// ---------------------------------------------------------------------------
static inline size_t rnd256(size_t b) { return (b + 255) & ~(size_t)255; }

extern "C" void kernel_launch(void* const* d_in, const int* in_sizes, int n_in,
                              void* d_out, int out_size, void* d_ws, size_t ws_size,
                              hipStream_t stream) {
    (void)in_sizes; (void)n_in;
    const float* x     = (const float*)d_in[0];
    const int*   ei    = (const int*)d_in[1];
    const int*   batch = (const int*)d_in[2];
    const int* src = ei;
    const int* dst = ei + N_EDGES;

    const float* c1_w1 = (const float*)d_in[3];
    const float* c1_b1 = (const float*)d_in[4];
    const float* c1_w2 = (const float*)d_in[5];
    const float* c1_b2 = (const float*)d_in[6];
    const float* c2_w1 = (const float*)d_in[7];
    const float* c2_b1 = (const float*)d_in[8];
    const float* c2_w2 = (const float*)d_in[9];
    const float* c2_b2 = (const float*)d_in[10];
    const float* c3_w1 = (const float*)d_in[11];
    const float* c3_b1 = (const float*)d_in[12];
    const float* c3_w2 = (const float*)d_in[13];
    const float* c3_b2 = (const float*)d_in[14];
    const float* lin_w1 = (const float*)d_in[15];
    const float* lin_b1 = (const float*)d_in[16];
    const float* lin_w2 = (const float*)d_in[17];
    const float* lin_b2 = (const float*)d_in[18];
    float* out = (float*)d_out;

    size_t off = 0;
    auto alloc = [&](size_t bytes) -> void* {
        void* p = (char*)d_ws + off;
        off += rnd256(bytes);
        return p;
    };
    u16*   b0        = (u16*)alloc((size_t)M_PAD * HID * 2);
    u16*   b1        = (u16*)alloc((size_t)M_PAD * HID * 2);
    float* agg7buf   = (float*)alloc((size_t)N_NODES * 7 * 4);
    int*   counts    = (int*)alloc((size_t)N_NODES * 4);
    int*   cursor    = (int*)alloc((size_t)N_NODES * 4);
    int*   row_start = (int*)alloc((size_t)(N_NODES + 1) * 4);
    int*   sorted_src= (int*)alloc((size_t)N_EDGES * 4);
    int*   g_start   = (int*)alloc((size_t)(N_GRAPHS + 1) * 4);
    int*   partials  = (int*)alloc((size_t)SCAN_NB * 4);
    float* pooled    = (float*)alloc((size_t)N_GRAPHS * HID * 4);
    char*  hh_slot   = (char*)alloc((size_t)N_GRAPHS * 256 * 4);
    float* hh        = (float*)hh_slot;
    u16*   wt        = (u16*)hh_slot;
    u16* c1w2T = wt + 0 * HID * HID;
    u16* c2w1T = wt + 1 * HID * HID;
    u16* c2w2T = wt + 2 * HID * HID;
    u16* c3w1T = wt + 3 * HID * HID;
    u16* c3w2T = wt + 4 * HID * HID;

    if (off > ws_size) {
        diag_kernel<<<(out_size + 255) / 256, 256, 0, stream>>>(
            out, out_size, (float)(ws_size >> 20));
        return;
    }

    // --- CSR build + weight prep ---
    zero_ints<<<(N_NODES + 255) / 256, 256, 0, stream>>>(counts, N_NODES);
    hist_kernel<<<(N_EDGES + 255) / 256, 256, 0, stream>>>(dst, counts);
    scan_chunks<<<SCAN_NB, 1024, 0, stream>>>(counts, row_start, partials);
    scan_partials<<<1, 64, 0, stream>>>(partials);
    scan_add_offsets<<<SCAN_NB, 1024, 0, stream>>>(row_start, partials);
    cursor_init<<<(N_NODES + 255) / 256, 256, 0, stream>>>(row_start, cursor);
    scatter_edges<<<(N_EDGES + 255) / 256, 256, 0, stream>>>(src, dst, cursor, sorted_src);
    graph_bounds<<<(N_GRAPHS + 256) / 256, 256, 0, stream>>>(batch, g_start);
    transpose5_to_bf16<<<dim3(HID / 32, HID / 32, 5), 256, 0, stream>>>(
        c1_w2, c2_w1, c2_w2, c3_w1, c3_w2, wt);

    dim3 mgrid(HID / 128, M_PAD / 128);   // 4 x 782
    const int aggGrid = N_NODES / 4;      // 25000

    // --- Layer 1 ---
    agg7_kernel<<<(N_NODES + 7) / 8, 64, 0, stream>>>(x, row_start, sorted_src, agg7buf);
    gemm_k7_relu<<<(N_NODES + 127) / 128, 256, 0, stream>>>(agg7buf, c1_w1, c1_b1, b0);
    gemm_mfma_bf16<true><<<mgrid, 256, 0, stream>>>(b0, c1w2T, c1_b2, b1);
    // --- Layer 2 ---
    agg_full<<<aggGrid, 256, 0, stream>>>(b1, row_start, sorted_src, b0);
    gemm_mfma_bf16<true><<<mgrid, 256, 0, stream>>>(b0, c2w1T, c2_b1, b1);
    gemm_mfma_bf16<true><<<mgrid, 256, 0, stream>>>(b1, c2w2T, c2_b2, b0);
    // --- Layer 3 ---
    agg_full<<<aggGrid, 256, 0, stream>>>(b0, row_start, sorted_src, b1);
    gemm_mfma_bf16<true><<<mgrid, 256, 0, stream>>>(b1, c3w1T, c3_b1, b0);
    gemm_mfma_bf16<true><<<mgrid, 256, 0, stream>>>(b0, c3w2T, c3_b2, b1);
    // --- Pool + head (fp32) ---
    pool_kernel<<<N_GRAPHS / 4, 256, 0, stream>>>(b1, g_start, pooled);
    gemm_tiled_f32<true><<<dim3(256 / 64, N_GRAPHS / 64), 256, 0, stream>>>(
        pooled, lin_w1, lin_b1, hh, N_GRAPHS, 256, HID);
    gemm_tiled_f32<false><<<dim3(1, N_GRAPHS / 64), 256, 0, stream>>>(
        hh, lin_w2, lin_b2, out, N_GRAPHS, OUT_DIM, 256);
}